// Round 10
// baseline (743.640 us; speedup 1.0000x reference)
//
#include <hip/hip_runtime.h>
#include <hip/hip_bf16.h>
#include <math.h>

#define N_NODES 65536
#define N_EDGES 262144
#define BATCHSZ 2048
#define F_IN    78
#define K1PAD   96
#define GENES   735
#define GOUT    512
#define HEADS   8
#define HID     64
#define TOT_E   (N_EDGES + N_NODES)   // 327680
#define RPB     4                     // batch rows per fused-MLP block

typedef unsigned short u16;
typedef unsigned int   u32;
typedef __attribute__((ext_vector_type(4))) float f32x4;
typedef __attribute__((ext_vector_type(8))) short bf16x8;

__device__ __forceinline__ float bf2f(u32 h) {
    u32 u = h << 16;
    return __uint_as_float(u);
}
__device__ __forceinline__ u16 f2bf(float f) {
    u32 u = __float_as_uint(f);
    u32 r = (u + 0x7FFFu + ((u >> 16) & 1u)) >> 16;   // round-to-nearest-even
    return (u16)r;
}

// ================= MFMA bf16 GEMM (node-feature GEMMs) =================
__global__ __launch_bounds__(256) void gemm_mfma(
    const u16* __restrict__ A, const u16* __restrict__ BT, u16* __restrict__ C,
    int M, int N, int K, int ldc)
{
    __shared__ u16 Al[128 * 40];
    __shared__ u16 Bl[128 * 40];
    int t    = threadIdx.x;
    int wid  = t >> 6, lane = t & 63;
    int wm   = wid >> 1, wn = wid & 1;
    int bm   = blockIdx.x * 128, bn = blockIdx.y * 128;

    f32x4 acc[4][4] = {};

    for (int k0 = 0; k0 < K; k0 += 32) {
        #pragma unroll
        for (int i = 0; i < 2; ++i) {
            int flat = t + i * 256;          // 0..511
            int row  = flat >> 2, slot = flat & 3;
            uint4 va = *(const uint4*)(A  + (size_t)(bm + row) * K + k0 + slot * 8);
            *(uint4*)(Al + row * 40 + slot * 8) = va;
            uint4 vb = *(const uint4*)(BT + (size_t)(bn + row) * K + k0 + slot * 8);
            *(uint4*)(Bl + row * 40 + slot * 8) = vb;
        }
        __syncthreads();
        bf16x8 af[4], bfr[4];
        int r0 = wm * 64 + (lane & 15);
        int c0 = wn * 64 + (lane & 15);
        int kk = (lane >> 4) * 8;
        #pragma unroll
        for (int m = 0; m < 4; ++m)
            af[m] = *(const bf16x8*)(Al + (r0 + m * 16) * 40 + kk);
        #pragma unroll
        for (int n = 0; n < 4; ++n)
            bfr[n] = *(const bf16x8*)(Bl + (c0 + n * 16) * 40 + kk);
        #pragma unroll
        for (int m = 0; m < 4; ++m)
            #pragma unroll
            for (int n = 0; n < 4; ++n)
                acc[m][n] = __builtin_amdgcn_mfma_f32_16x16x32_bf16(af[m], bfr[n], acc[m][n], 0, 0, 0);
        __syncthreads();
    }
    int rbase = bm + wm * 64 + (lane >> 4) * 4;
    int cbase = bn + wn * 64 + (lane & 15);
    #pragma unroll
    for (int m = 0; m < 4; ++m)
        #pragma unroll
        for (int n = 0; n < 4; ++n) {
            int col = cbase + n * 16;
            #pragma unroll
            for (int j = 0; j < 4; ++j) {
                int row = rbase + m * 16 + j;
                C[(size_t)row * ldc + col] = f2bf(acc[m][n][j]);
            }
        }
}

// ---- weight/input conversion: f32 -> bf16 (optionally transposed / K-padded) ----
__global__ void conv_x_pad(const float* __restrict__ x, u16* __restrict__ xb) {
    int i = blockIdx.x * 256 + threadIdx.x;          // over N_NODES*K1PAD
    int row = i / K1PAD, col = i - row * K1PAD;
    xb[i] = (col < F_IN) ? f2bf(x[(size_t)row * F_IN + col]) : (u16)0;
}
__global__ void conv_w1t(const float* __restrict__ W, u16* __restrict__ WT) {
    int i = blockIdx.x * 256 + threadIdx.x;          // over GOUT*K1PAD
    int n = i / K1PAD, k = i - n * K1PAD;
    WT[i] = (k < F_IN) ? f2bf(W[(size_t)k * GOUT + n]) : (u16)0;
}
__global__ void conv_w2t(const float* __restrict__ W, u16* __restrict__ WT) {
    int i = blockIdx.x * 256 + threadIdx.x;          // over GOUT*GOUT
    int n = i >> 9, k = i & 511;
    WT[i] = f2bf(W[(size_t)k * GOUT + n]);
}

// ================= fused MLP: geno encoder + fusion head, RPB rows/block =================
// Per row: z1 = relu(bn(x_gen@gW1+gb1))[128]; z2 = relu(z1@gW2+gb2)[512];
// c = [g | z2][1024]; f1 = relu(c@fW1+fb1)[256]; f2 = relu(f1@fW2+fb2)[128];
// out = f2@fW3 + fb3.
// Register-blocked over RPB rows: every weight load feeds RPB FMAs.
__global__ __launch_bounds__(256) void fused_mlp(
    const float* __restrict__ x_gen, const float* __restrict__ cbuf,
    const float* __restrict__ gW1, const float* __restrict__ gb1,
    const float* __restrict__ bng, const float* __restrict__ bnb,
    const float* __restrict__ bnm, const float* __restrict__ bnv,
    const float* __restrict__ gW2, const float* __restrict__ gb2,
    const float* __restrict__ fW1, const float* __restrict__ fb1,
    const float* __restrict__ fW2, const float* __restrict__ fb2,
    const float* __restrict__ fW3, const float* __restrict__ fb3,
    float* __restrict__ out)
{
    __shared__ float xs[RPB][GENES];     // 11760 B
    __shared__ float cs[RPB][1024];      // 16384 B  [g | z2]
    __shared__ float z1[RPB][128];       //  2048 B
    __shared__ float f1[RPB][256];       //  4096 B
    __shared__ float f2[RPB][128];       //  2048 B
    __shared__ float red[2][RPB][128];   //  4096 B  split-K scratch
    int tid  = threadIdx.x;
    int row0 = blockIdx.x * RPB;

    #pragma unroll
    for (int r = 0; r < RPB; ++r) {
        for (int k = tid; k < GENES; k += 256)
            xs[r][k] = x_gen[(size_t)(row0 + r) * GENES + k];
        for (int k = tid; k < 512; k += 256)
            cs[r][k] = cbuf[(size_t)(row0 + r) * 1024 + k];
    }
    __syncthreads();

    // ---- phase 1: z1 = relu(bn(x@gW1)), N=128, K=735, split-K x2 ----
    {
        int j = tid & 127, half = tid >> 7;
        int k0 = half * 368, k1 = half ? GENES : 368;
        float a[RPB] = {};
        for (int k = k0; k < k1; ++k) {
            float b = gW1[(size_t)k * 128 + j];
            #pragma unroll
            for (int r = 0; r < RPB; ++r) a[r] += xs[r][k] * b;
        }
        #pragma unroll
        for (int r = 0; r < RPB; ++r) red[half][r][j] = a[r];
    }
    __syncthreads();
    {
        // 512 combine tasks (4 rows x 128 cols), 2 per thread
        #pragma unroll
        for (int i = 0; i < 2; ++i) {
            int task = tid + i * 256;
            int r = task >> 7, j = task & 127;
            float v = red[0][r][j] + red[1][r][j];
            float s = bng[j] * rsqrtf(bnv[j] + 1e-5f);
            v = (v + gb1[j] - bnm[j]) * s + bnb[j];
            z1[r][j] = fmaxf(v, 0.f);
        }
    }
    __syncthreads();

    // ---- phase 2: z2 = relu(z1@gW2+gb2) -> cs[:,512+], N=512, K=128 ----
    {
        int j0 = tid, j1 = tid + 256;
        float a0[RPB] = {}, a1[RPB] = {};
        for (int k = 0; k < 128; ++k) {
            float b0 = gW2[(size_t)k * 512 + j0];
            float b1 = gW2[(size_t)k * 512 + j1];
            #pragma unroll
            for (int r = 0; r < RPB; ++r) {
                float z = z1[r][k];
                a0[r] += z * b0;
                a1[r] += z * b1;
            }
        }
        #pragma unroll
        for (int r = 0; r < RPB; ++r) {
            cs[r][512 + j0] = fmaxf(a0[r] + gb2[j0], 0.f);
            cs[r][512 + j1] = fmaxf(a1[r] + gb2[j1], 0.f);
        }
    }
    __syncthreads();

    // ---- phase 3: f1 = relu(c@fW1+fb1), N=256, K=1024 ----
    {
        int j = tid;
        float a[RPB] = {};
        for (int k = 0; k < 1024; ++k) {
            float b = fW1[(size_t)k * 256 + j];
            #pragma unroll
            for (int r = 0; r < RPB; ++r) a[r] += cs[r][k] * b;
        }
        #pragma unroll
        for (int r = 0; r < RPB; ++r)
            f1[r][j] = fmaxf(a[r] + fb1[j], 0.f);
    }
    __syncthreads();

    // ---- phase 4: f2 = relu(f1@fW2+fb2), N=128, K=256, split-K x2 ----
    {
        int j = tid & 127, half = tid >> 7;
        int k0 = half * 128, k1 = k0 + 128;
        float a[RPB] = {};
        for (int k = k0; k < k1; ++k) {
            float b = fW2[(size_t)k * 128 + j];
            #pragma unroll
            for (int r = 0; r < RPB; ++r) a[r] += f1[r][k] * b;
        }
        #pragma unroll
        for (int r = 0; r < RPB; ++r) red[half][r][j] = a[r];
    }
    __syncthreads();
    {
        #pragma unroll
        for (int i = 0; i < 2; ++i) {
            int task = tid + i * 256;
            int r = task >> 7, j = task & 127;
            float v = red[0][r][j] + red[1][r][j] + fb2[j];
            f2[r][j] = fmaxf(v, 0.f);
        }
    }
    __syncthreads();

    // ---- phase 5: out = f2@fW3 + fb3; wave w handles row w ----
    {
        int r = tid >> 6, l = tid & 63;
        float v = f2[r][l] * fW3[l] + f2[r][l + 64] * fW3[l + 64];
        v += __shfl_xor(v, 32); v += __shfl_xor(v, 16); v += __shfl_xor(v, 8);
        v += __shfl_xor(v, 4);  v += __shfl_xor(v, 2);  v += __shfl_xor(v, 1);
        if (l == 0) out[row0 + r] = v + fb3[0];
    }
}

// ---------------- attention coefficients from bf16 features ----------------
__global__ __launch_bounds__(256) void gat_att(
    const u16* __restrict__ h,
    const float* __restrict__ att_src, const float* __restrict__ att_dst,
    float* __restrict__ aS, float* __restrict__ aD)
{
    int gid  = blockIdx.x * blockDim.x + threadIdx.x;
    int n    = gid >> 6;
    int lane = threadIdx.x & 63;
    if (n >= N_NODES) return;
    int head = lane >> 3;
    int ci   = (lane & 7) * 8;
    uint4 q = *(const uint4*)(h + (size_t)n * GOUT + lane * 8);
    float h0 = bf2f(q.x & 0xffff), h1 = bf2f(q.x >> 16);
    float h2 = bf2f(q.y & 0xffff), h3 = bf2f(q.y >> 16);
    float h4 = bf2f(q.z & 0xffff), h5 = bf2f(q.z >> 16);
    float h6 = bf2f(q.w & 0xffff), h7 = bf2f(q.w >> 16);
    const float* as = att_src + head * HID + ci;
    const float* ad = att_dst + head * HID + ci;
    float ss = h0*as[0] + h1*as[1] + h2*as[2] + h3*as[3]
             + h4*as[4] + h5*as[5] + h6*as[6] + h7*as[7];
    float dd = h0*ad[0] + h1*ad[1] + h2*ad[2] + h3*ad[3]
             + h4*ad[4] + h5*ad[5] + h6*ad[6] + h7*ad[7];
    ss += __shfl_xor(ss, 1); ss += __shfl_xor(ss, 2); ss += __shfl_xor(ss, 4);
    dd += __shfl_xor(dd, 1); dd += __shfl_xor(dd, 2); dd += __shfl_xor(dd, 4);
    if ((lane & 7) == 0) {
        aS[n * HEADS + head] = ss;
        aD[n * HEADS + head] = dd;
    }
}

// ---------------- CSR build ----------------
__global__ void k_init_counts(int* cnt) {
    int i = blockIdx.x * 256 + threadIdx.x;
    if (i < N_NODES) cnt[i] = 1;             // self-loop
}
__global__ void k_count(const int* __restrict__ dst, int* cnt) {
    int e = blockIdx.x * 256 + threadIdx.x;
    if (e < N_EDGES) atomicAdd(&cnt[dst[e]], 1);
}
__global__ void k_scan1(const int* __restrict__ cnt, int* __restrict__ off, int* __restrict__ bsum) {
    __shared__ int s[256];
    int b = blockIdx.x, t = threadIdx.x;
    s[t] = cnt[b * 256 + t]; __syncthreads();
    for (int d = 1; d < 256; d <<= 1) {
        int x = (t >= d) ? s[t - d] : 0;
        __syncthreads();
        s[t] += x;
        __syncthreads();
    }
    off[b * 256 + t + 1] = s[t];
    if (t == 255) bsum[b] = s[255];
}
__global__ void k_scan2(int* bsum) {
    __shared__ int s[256];
    int t = threadIdx.x;
    s[t] = bsum[t]; __syncthreads();
    for (int d = 1; d < 256; d <<= 1) {
        int x = (t >= d) ? s[t - d] : 0;
        __syncthreads();
        s[t] += x;
        __syncthreads();
    }
    bsum[t] = s[t];
}
__global__ void k_scan3(int* __restrict__ off, const int* __restrict__ bsum) {
    int b = blockIdx.x, t = threadIdx.x;
    if (b > 0) off[b * 256 + t + 1] += bsum[b - 1];
    if (b == 0 && t == 0) off[0] = 0;
}
__global__ void k_copy(const int* __restrict__ off, int* __restrict__ cur) {
    int i = blockIdx.x * 256 + threadIdx.x;
    if (i < N_NODES) cur[i] = off[i];
}
__global__ void k_fill(const int* __restrict__ esrc, const int* __restrict__ edst,
                       int* cur, int* __restrict__ srcs, int* __restrict__ dsts) {
    int i = blockIdx.x * 256 + threadIdx.x;
    if (i >= TOT_E) return;
    int s, d;
    if (i < N_EDGES) { s = esrc[i]; d = edst[i]; }
    else             { s = d = i - N_EDGES; }
    int p = atomicAdd(&cur[d], 1);
    srcs[p] = s;
    dsts[p] = d;
}

// ---------------- per-(edge,head) unnormalized attention weight ----------------
__global__ __launch_bounds__(256) void edge_alpha(
    const int* __restrict__ srcs, const int* __restrict__ dsts,
    const float* __restrict__ aS, const float* __restrict__ aD,
    float* __restrict__ ealpha)
{
    int i = blockIdx.x * 256 + threadIdx.x;      // over TOT_E*HEADS
    int o = i >> 3, h = i & 7;
    int s = srcs[o], d = dsts[o];
    float x = aS[s * HEADS + h] + aD[d * HEADS + h];
    x = x > 0.f ? x : 0.2f * x;
    ealpha[i] = expf(x);
}

// ---------------- GAT aggregation: single pass, precomputed weights ----------------
__global__ __launch_bounds__(256) void gat_aggregate(
    const u16* __restrict__ h, const float* __restrict__ ealpha,
    const int* __restrict__ off, const int* __restrict__ srcs,
    const float* __restrict__ bias, u16* __restrict__ out)
{
    int gid  = blockIdx.x * blockDim.x + threadIdx.x;
    int n    = gid >> 6;
    if (n >= N_NODES) return;
    int lane = threadIdx.x & 63;
    int head = lane >> 3;
    int o0 = off[n], o1 = off[n + 1];
    float denom = 0.f;
    float acc[8] = {};
    for (int o = o0; o < o1; ++o) {
        int s = srcs[o];
        float e = ealpha[o * HEADS + head];
        denom += e;
        uint4 q = *(const uint4*)(h + (size_t)s * GOUT + lane * 8);
        acc[0] += e * bf2f(q.x & 0xffff); acc[1] += e * bf2f(q.x >> 16);
        acc[2] += e * bf2f(q.y & 0xffff); acc[3] += e * bf2f(q.y >> 16);
        acc[4] += e * bf2f(q.z & 0xffff); acc[5] += e * bf2f(q.z >> 16);
        acc[6] += e * bf2f(q.w & 0xffff); acc[7] += e * bf2f(q.w >> 16);
    }
    float inv = 1.f / (denom + 1e-16f);
    int c0 = lane * 8;
    float r[8];
    #pragma unroll
    for (int j = 0; j < 8; ++j) {
        float v = acc[j] * inv + bias[c0 + j];
        r[j] = v > 0.f ? v : expm1f(v);
    }
    uint4 w;
    w.x = (u32)f2bf(r[0]) | ((u32)f2bf(r[1]) << 16);
    w.y = (u32)f2bf(r[2]) | ((u32)f2bf(r[3]) << 16);
    w.z = (u32)f2bf(r[4]) | ((u32)f2bf(r[5]) << 16);
    w.w = (u32)f2bf(r[6]) | ((u32)f2bf(r[7]) << 16);
    *(uint4*)(out + (size_t)n * GOUT + c0) = w;
}

// ---------------- global mean pool ----------------
__global__ __launch_bounds__(256) void pool_kernel(
    const u16* __restrict__ x, const int* __restrict__ batch, float* __restrict__ cbuf)
{
    int b = blockIdx.x;
    int lo = 0, hi = N_NODES;
    while (lo < hi) { int mid = (lo + hi) >> 1; if (batch[mid] < b) lo = mid + 1; else hi = mid; }
    int start = lo;
    hi = N_NODES;
    while (lo < hi) { int mid = (lo + hi) >> 1; if (batch[mid] < b + 1) lo = mid + 1; else hi = mid; }
    int end = lo;
    int t = threadIdx.x;
    float s0 = 0.f, s1 = 0.f;
    for (int i = start; i < end; ++i) {
        s0 += bf2f(x[(size_t)i * GOUT + t]);
        s1 += bf2f(x[(size_t)i * GOUT + t + 256]);
    }
    float sc = 1.f / fmaxf((float)(end - start), 1.f);
    cbuf[(size_t)b * 1024 + t]       = s0 * sc;
    cbuf[(size_t)b * 1024 + t + 256] = s1 * sc;
}

extern "C" void kernel_launch(void* const* d_in, const int* in_sizes, int n_in,
                              void* d_out, int out_size, void* d_ws, size_t ws_size,
                              hipStream_t stream)
{
    const float* x     = (const float*)d_in[0];
    const int*   ei    = (const int*)  d_in[1];
    const int*   batch = (const int*)  d_in[2];
    const float* x_gen = (const float*)d_in[3];
    const float* W1    = (const float*)d_in[4];
    const float* as1   = (const float*)d_in[5];
    const float* ad1   = (const float*)d_in[6];
    const float* b1    = (const float*)d_in[7];
    const float* W2    = (const float*)d_in[8];
    const float* as2   = (const float*)d_in[9];
    const float* ad2   = (const float*)d_in[10];
    const float* b2    = (const float*)d_in[11];
    const float* gW1   = (const float*)d_in[12];
    const float* gb1   = (const float*)d_in[13];
    const float* bng   = (const float*)d_in[14];
    const float* bnb   = (const float*)d_in[15];
    const float* bnm   = (const float*)d_in[16];
    const float* bnv   = (const float*)d_in[17];
    const float* gW2   = (const float*)d_in[18];
    const float* gb2   = (const float*)d_in[19];
    const float* fW1   = (const float*)d_in[20];
    const float* fb1   = (const float*)d_in[21];
    const float* fW2   = (const float*)d_in[22];
    const float* fb2   = (const float*)d_in[23];
    const float* fW3   = (const float*)d_in[24];
    const float* fb3   = (const float*)d_in[25];
    float* out = (float*)d_out;

    char* ws = (char*)d_ws;
    size_t off_b = 0;
    auto alloc = [&](size_t bytes) -> void* {
        void* p = ws + off_b;
        off_b += (bytes + 255) & ~(size_t)255;
        return p;
    };
    u16*   bufA    = (u16*)  alloc((size_t)N_NODES * GOUT * 2);   // bf16 features
    u16*   bufB    = (u16*)  alloc((size_t)N_NODES * GOUT * 2);   // bf16 features
    u16*   xb      = (u16*)  alloc((size_t)N_NODES * K1PAD * 2);  // x bf16, K-padded
    u16*   w1t     = (u16*)  alloc((size_t)GOUT * K1PAD * 2);     // W1^T bf16 padded
    u16*   w2t     = (u16*)  alloc((size_t)GOUT * GOUT * 2);      // W2^T bf16
    float* aSp     = (float*)alloc((size_t)N_NODES * HEADS * 4);
    float* aDp     = (float*)alloc((size_t)N_NODES * HEADS * 4);
    int*   csr_off = (int*)  alloc((size_t)(N_NODES + 1) * 4);
    int*   csr_cur = (int*)  alloc((size_t)N_NODES * 4);
    int*   bsum    = (int*)  alloc(256 * 4);
    int*   csr_src = (int*)  alloc((size_t)TOT_E * 4);
    int*   csr_dst = (int*)  alloc((size_t)TOT_E * 4);
    float* ealpha  = (float*)alloc((size_t)TOT_E * HEADS * 4);
    float* cbuf    = (float*)alloc((size_t)BATCHSZ * 1024 * 4);   // [g | unused]
    
    if (off_b > ws_size) return;   // clean no-op beats a memory fault

    const int* esrc = ei;
    const int* edst = ei + N_EDGES;

    // ---- conversions (bf16 weights/inputs for MFMA) ----
    conv_x_pad<<<(N_NODES * K1PAD) / 256, 256, 0, stream>>>(x, xb);
    conv_w1t<<<(GOUT * K1PAD) / 256, 256, 0, stream>>>(W1, w1t);
    conv_w2t<<<(GOUT * GOUT) / 256, 256, 0, stream>>>(W2, w2t);

    // ---- CSR by destination ----
    k_init_counts<<<N_NODES / 256, 256, 0, stream>>>(csr_cur);
    k_count<<<N_EDGES / 256, 256, 0, stream>>>(edst, csr_cur);
    k_scan1<<<256, 256, 0, stream>>>(csr_cur, csr_off, bsum);
    k_scan2<<<1, 256, 0, stream>>>(bsum);
    k_scan3<<<256, 256, 0, stream>>>(csr_off, bsum);
    k_copy<<<N_NODES / 256, 256, 0, stream>>>(csr_off, csr_cur);
    k_fill<<<TOT_E / 256, 256, 0, stream>>>(esrc, edst, csr_cur, csr_src, csr_dst);

    // ---- GAT layer 1 (MFMA) ----
    dim3 gMF(N_NODES / 128, GOUT / 128);
    gemm_mfma<<<gMF, 256, 0, stream>>>(xb, w1t, bufA, N_NODES, GOUT, K1PAD, GOUT);
    gat_att<<<N_NODES / 4, 256, 0, stream>>>(bufA, as1, ad1, aSp, aDp);
    edge_alpha<<<(TOT_E * HEADS) / 256, 256, 0, stream>>>(csr_src, csr_dst, aSp, aDp, ealpha);
    gat_aggregate<<<N_NODES / 4, 256, 0, stream>>>(bufA, ealpha, csr_off, csr_src, b1, bufB);

    // ---- GAT layer 2 (MFMA) ----
    gemm_mfma<<<gMF, 256, 0, stream>>>(bufB, w2t, bufA, N_NODES, GOUT, GOUT, GOUT);
    gat_att<<<N_NODES / 4, 256, 0, stream>>>(bufA, as2, ad2, aSp, aDp);
    edge_alpha<<<(TOT_E * HEADS) / 256, 256, 0, stream>>>(csr_src, csr_dst, aSp, aDp, ealpha);
    gat_aggregate<<<N_NODES / 4, 256, 0, stream>>>(bufA, ealpha, csr_off, csr_src, b2, bufB);

    // ---- pool (writes g into cbuf[:, 0:512)) ----
    pool_kernel<<<BATCHSZ, 256, 0, stream>>>(bufB, batch, cbuf);

    // ---- fused MLP: geno encoder + fusion head + final dot ----
    fused_mlp<<<BATCHSZ / RPB, 256, 0, stream>>>(
        x_gen, cbuf,
        gW1, gb1, bng, bnb, bnm, bnv,
        gW2, gb2, fW1, fb1, fW2, fb2, fW3, fb3,
        out);
}

// Round 12
// 610.009 us; speedup vs baseline: 1.2191x; 1.2191x over previous
//
#include <hip/hip_runtime.h>
#include <hip/hip_bf16.h>
#include <math.h>

#define N_NODES 65536
#define N_EDGES 262144
#define BATCHSZ 2048
#define F_IN    78
#define K1PAD   96
#define GENES   735
#define GOUT    512
#define HEADS   8
#define HID     64
#define TOT_E   (N_EDGES + N_NODES)   // 327680
#define RPB     4                     // batch rows per fused-MLP block

typedef unsigned short u16;
typedef unsigned int   u32;
typedef __attribute__((ext_vector_type(4))) float f32x4;
typedef __attribute__((ext_vector_type(8))) short bf16x8;

__device__ __forceinline__ float bf2f(u32 h) {
    u32 u = h << 16;
    return __uint_as_float(u);
}
__device__ __forceinline__ u16 f2bf(float f) {
    u32 u = __float_as_uint(f);
    u32 r = (u + 0x7FFFu + ((u >> 16) & 1u)) >> 16;   // round-to-nearest-even
    return (u16)r;
}

// ================= MFMA bf16 GEMM (node-feature GEMMs) =================
__global__ __launch_bounds__(256) void gemm_mfma(
    const u16* __restrict__ A, const u16* __restrict__ BT, u16* __restrict__ C,
    int M, int N, int K, int ldc)
{
    __shared__ u16 Al[128 * 40];
    __shared__ u16 Bl[128 * 40];
    int t    = threadIdx.x;
    int wid  = t >> 6, lane = t & 63;
    int wm   = wid >> 1, wn = wid & 1;
    int bm   = blockIdx.x * 128, bn = blockIdx.y * 128;

    f32x4 acc[4][4] = {};

    for (int k0 = 0; k0 < K; k0 += 32) {
        #pragma unroll
        for (int i = 0; i < 2; ++i) {
            int flat = t + i * 256;          // 0..511
            int row  = flat >> 2, slot = flat & 3;
            uint4 va = *(const uint4*)(A  + (size_t)(bm + row) * K + k0 + slot * 8);
            *(uint4*)(Al + row * 40 + slot * 8) = va;
            uint4 vb = *(const uint4*)(BT + (size_t)(bn + row) * K + k0 + slot * 8);
            *(uint4*)(Bl + row * 40 + slot * 8) = vb;
        }
        __syncthreads();
        bf16x8 af[4], bfr[4];
        int r0 = wm * 64 + (lane & 15);
        int c0 = wn * 64 + (lane & 15);
        int kk = (lane >> 4) * 8;
        #pragma unroll
        for (int m = 0; m < 4; ++m)
            af[m] = *(const bf16x8*)(Al + (r0 + m * 16) * 40 + kk);
        #pragma unroll
        for (int n = 0; n < 4; ++n)
            bfr[n] = *(const bf16x8*)(Bl + (c0 + n * 16) * 40 + kk);
        #pragma unroll
        for (int m = 0; m < 4; ++m)
            #pragma unroll
            for (int n = 0; n < 4; ++n)
                acc[m][n] = __builtin_amdgcn_mfma_f32_16x16x32_bf16(af[m], bfr[n], acc[m][n], 0, 0, 0);
        __syncthreads();
    }
    int rbase = bm + wm * 64 + (lane >> 4) * 4;
    int cbase = bn + wn * 64 + (lane & 15);
    #pragma unroll
    for (int m = 0; m < 4; ++m)
        #pragma unroll
        for (int n = 0; n < 4; ++n) {
            int col = cbase + n * 16;
            #pragma unroll
            for (int j = 0; j < 4; ++j) {
                int row = rbase + m * 16 + j;
                C[(size_t)row * ldc + col] = f2bf(acc[m][n][j]);
            }
        }
}

// ---- weight/input conversion: f32 -> bf16 (optionally transposed / K-padded) ----
__global__ void conv_x_pad(const float* __restrict__ x, u16* __restrict__ xb) {
    int i = blockIdx.x * 256 + threadIdx.x;          // over N_NODES*K1PAD
    int row = i / K1PAD, col = i - row * K1PAD;
    xb[i] = (col < F_IN) ? f2bf(x[(size_t)row * F_IN + col]) : (u16)0;
}
__global__ void conv_w1t(const float* __restrict__ W, u16* __restrict__ WT) {
    int i = blockIdx.x * 256 + threadIdx.x;          // over GOUT*K1PAD
    int n = i / K1PAD, k = i - n * K1PAD;
    WT[i] = (k < F_IN) ? f2bf(W[(size_t)k * GOUT + n]) : (u16)0;
}
__global__ void conv_w2t(const float* __restrict__ W, u16* __restrict__ WT) {
    int i = blockIdx.x * 256 + threadIdx.x;          // over GOUT*GOUT
    int n = i >> 9, k = i & 511;
    WT[i] = f2bf(W[(size_t)k * GOUT + n]);
}

// ================= fused MLP: geno encoder + fusion head, RPB rows/block =================
// Inner loops: K unrolled by 8 -> 8 independent global weight loads batched per
// vmcnt wait (latency amortized 8x), LDS activations read as float4 (b128).
__global__ __launch_bounds__(256) void fused_mlp(
    const float* __restrict__ x_gen, const float* __restrict__ cbuf,
    const float* __restrict__ gW1, const float* __restrict__ gb1,
    const float* __restrict__ bng, const float* __restrict__ bnb,
    const float* __restrict__ bnm, const float* __restrict__ bnv,
    const float* __restrict__ gW2, const float* __restrict__ gb2,
    const float* __restrict__ fW1, const float* __restrict__ fb1,
    const float* __restrict__ fW2, const float* __restrict__ fb2,
    const float* __restrict__ fW3, const float* __restrict__ fb3,
    float* __restrict__ out)
{
    __shared__ float xs[RPB][736];       // 11776 B (736: 16B-aligned rows, 735 used)
    __shared__ float cs[RPB][1024];      // 16384 B  [g | z2]
    __shared__ float z1[RPB][128];       //  2048 B
    __shared__ float f1[RPB][256];       //  4096 B
    __shared__ float f2[RPB][128];       //  2048 B
    __shared__ float red[2][RPB][128];   //  4096 B  split-K scratch
    int tid  = threadIdx.x;
    int row0 = blockIdx.x * RPB;

    #pragma unroll
    for (int r = 0; r < RPB; ++r) {
        for (int k = tid; k < GENES; k += 256)
            xs[r][k] = x_gen[(size_t)(row0 + r) * GENES + k];
        for (int k = tid; k < 512; k += 256)
            cs[r][k] = cbuf[(size_t)(row0 + r) * 1024 + k];
    }
    if (tid < RPB) xs[tid][735] = 0.f;
    __syncthreads();

    // ---- phase 1: z1 = relu(bn(x@gW1)), N=128, K=735, split-K x2, unroll 8 ----
    {
        int j = tid & 127, half = tid >> 7;
        int k0 = half * 368, kend = half ? GENES : 368;
        float a[RPB] = {};
        int k = k0;
        for (; k + 8 <= kend; k += 8) {
            float bv[8];
            #pragma unroll
            for (int u = 0; u < 8; ++u) bv[u] = gW1[(size_t)(k + u) * 128 + j];
            #pragma unroll
            for (int r = 0; r < RPB; ++r) {
                float4 x0 = *(const float4*)&xs[r][k];
                float4 x1 = *(const float4*)&xs[r][k + 4];
                a[r] += x0.x*bv[0] + x0.y*bv[1] + x0.z*bv[2] + x0.w*bv[3]
                      + x1.x*bv[4] + x1.y*bv[5] + x1.z*bv[6] + x1.w*bv[7];
            }
        }
        for (; k < kend; ++k) {
            float b = gW1[(size_t)k * 128 + j];
            #pragma unroll
            for (int r = 0; r < RPB; ++r) a[r] += xs[r][k] * b;
        }
        #pragma unroll
        for (int r = 0; r < RPB; ++r) red[half][r][j] = a[r];
    }
    __syncthreads();
    {
        #pragma unroll
        for (int i = 0; i < 2; ++i) {
            int task = tid + i * 256;
            int r = task >> 7, j = task & 127;
            float v = red[0][r][j] + red[1][r][j];
            float s = bng[j] * rsqrtf(bnv[j] + 1e-5f);
            v = (v + gb1[j] - bnm[j]) * s + bnb[j];
            z1[r][j] = fmaxf(v, 0.f);
        }
    }
    __syncthreads();

    // ---- phase 2: z2 = relu(z1@gW2+gb2) -> cs[:,512+], N=512, K=128, unroll 4 ----
    {
        int j0 = tid, j1 = tid + 256;
        float a0[RPB] = {}, a1[RPB] = {};
        for (int k = 0; k < 128; k += 4) {
            float b0[4], b1[4];
            #pragma unroll
            for (int u = 0; u < 4; ++u) {
                b0[u] = gW2[(size_t)(k + u) * 512 + j0];
                b1[u] = gW2[(size_t)(k + u) * 512 + j1];
            }
            #pragma unroll
            for (int r = 0; r < RPB; ++r) {
                float4 zv = *(const float4*)&z1[r][k];
                a0[r] += zv.x*b0[0] + zv.y*b0[1] + zv.z*b0[2] + zv.w*b0[3];
                a1[r] += zv.x*b1[0] + zv.y*b1[1] + zv.z*b1[2] + zv.w*b1[3];
            }
        }
        #pragma unroll
        for (int r = 0; r < RPB; ++r) {
            cs[r][512 + j0] = fmaxf(a0[r] + gb2[j0], 0.f);
            cs[r][512 + j1] = fmaxf(a1[r] + gb2[j1], 0.f);
        }
    }
    __syncthreads();

    // ---- phase 3: f1 = relu(c@fW1+fb1), N=256, K=1024, unroll 8 ----
    {
        int j = tid;
        float a[RPB] = {};
        for (int k = 0; k < 1024; k += 8) {
            float bv[8];
            #pragma unroll
            for (int u = 0; u < 8; ++u) bv[u] = fW1[(size_t)(k + u) * 256 + j];
            #pragma unroll
            for (int r = 0; r < RPB; ++r) {
                float4 c0 = *(const float4*)&cs[r][k];
                float4 c1 = *(const float4*)&cs[r][k + 4];
                a[r] += c0.x*bv[0] + c0.y*bv[1] + c0.z*bv[2] + c0.w*bv[3]
                      + c1.x*bv[4] + c1.y*bv[5] + c1.z*bv[6] + c1.w*bv[7];
            }
        }
        #pragma unroll
        for (int r = 0; r < RPB; ++r)
            f1[r][j] = fmaxf(a[r] + fb1[j], 0.f);
    }
    __syncthreads();

    // ---- phase 4: f2 = relu(f1@fW2+fb2), N=128, K=256, split-K x2, unroll 8 ----
    {
        int j = tid & 127, half = tid >> 7;
        int k0 = half * 128;
        float a[RPB] = {};
        for (int k = k0; k < k0 + 128; k += 8) {
            float bv[8];
            #pragma unroll
            for (int u = 0; u < 8; ++u) bv[u] = fW2[(size_t)(k + u) * 128 + j];
            #pragma unroll
            for (int r = 0; r < RPB; ++r) {
                float4 c0 = *(const float4*)&f1[r][k];
                float4 c1 = *(const float4*)&f1[r][k + 4];
                a[r] += c0.x*bv[0] + c0.y*bv[1] + c0.z*bv[2] + c0.w*bv[3]
                      + c1.x*bv[4] + c1.y*bv[5] + c1.z*bv[6] + c1.w*bv[7];
            }
        }
        #pragma unroll
        for (int r = 0; r < RPB; ++r) red[half][r][j] = a[r];
    }
    __syncthreads();
    {
        #pragma unroll
        for (int i = 0; i < 2; ++i) {
            int task = tid + i * 256;
            int r = task >> 7, j = task & 127;
            float v = red[0][r][j] + red[1][r][j] + fb2[j];
            f2[r][j] = fmaxf(v, 0.f);
        }
    }
    __syncthreads();

    // ---- phase 5: out = f2@fW3 + fb3; wave w handles row w ----
    {
        int r = tid >> 6, l = tid & 63;
        float v = f2[r][l] * fW3[l] + f2[r][l + 64] * fW3[l + 64];
        v += __shfl_xor(v, 32); v += __shfl_xor(v, 16); v += __shfl_xor(v, 8);
        v += __shfl_xor(v, 4);  v += __shfl_xor(v, 2);  v += __shfl_xor(v, 1);
        if (l == 0) out[row0 + r] = v + fb3[0];
    }
}

// ---------------- attention coefficients from bf16 features ----------------
__global__ __launch_bounds__(256) void gat_att(
    const u16* __restrict__ h,
    const float* __restrict__ att_src, const float* __restrict__ att_dst,
    float* __restrict__ aS, float* __restrict__ aD)
{
    int gid  = blockIdx.x * blockDim.x + threadIdx.x;
    int n    = gid >> 6;
    int lane = threadIdx.x & 63;
    if (n >= N_NODES) return;
    int head = lane >> 3;
    int ci   = (lane & 7) * 8;
    uint4 q = *(const uint4*)(h + (size_t)n * GOUT + lane * 8);
    float h0 = bf2f(q.x & 0xffff), h1 = bf2f(q.x >> 16);
    float h2 = bf2f(q.y & 0xffff), h3 = bf2f(q.y >> 16);
    float h4 = bf2f(q.z & 0xffff), h5 = bf2f(q.z >> 16);
    float h6 = bf2f(q.w & 0xffff), h7 = bf2f(q.w >> 16);
    const float* as = att_src + head * HID + ci;
    const float* ad = att_dst + head * HID + ci;
    float ss = h0*as[0] + h1*as[1] + h2*as[2] + h3*as[3]
             + h4*as[4] + h5*as[5] + h6*as[6] + h7*as[7];
    float dd = h0*ad[0] + h1*ad[1] + h2*ad[2] + h3*ad[3]
             + h4*ad[4] + h5*ad[5] + h6*ad[6] + h7*ad[7];
    ss += __shfl_xor(ss, 1); ss += __shfl_xor(ss, 2); ss += __shfl_xor(ss, 4);
    dd += __shfl_xor(dd, 1); dd += __shfl_xor(dd, 2); dd += __shfl_xor(dd, 4);
    if ((lane & 7) == 0) {
        aS[n * HEADS + head] = ss;
        aD[n * HEADS + head] = dd;
    }
}

// ---------------- CSR build ----------------
__global__ void k_init_counts(int* cnt) {
    int i = blockIdx.x * 256 + threadIdx.x;
    if (i < N_NODES) cnt[i] = 1;             // self-loop
}
__global__ void k_count(const int* __restrict__ dst, int* cnt) {
    int e = blockIdx.x * 256 + threadIdx.x;
    if (e < N_EDGES) atomicAdd(&cnt[dst[e]], 1);
}
__global__ void k_scan1(const int* __restrict__ cnt, int* __restrict__ off, int* __restrict__ bsum) {
    __shared__ int s[256];
    int b = blockIdx.x, t = threadIdx.x;
    s[t] = cnt[b * 256 + t]; __syncthreads();
    for (int d = 1; d < 256; d <<= 1) {
        int x = (t >= d) ? s[t - d] : 0;
        __syncthreads();
        s[t] += x;
        __syncthreads();
    }
    off[b * 256 + t + 1] = s[t];
    if (t == 255) bsum[b] = s[255];
}
__global__ void k_scan2(int* bsum) {
    __shared__ int s[256];
    int t = threadIdx.x;
    s[t] = bsum[t]; __syncthreads();
    for (int d = 1; d < 256; d <<= 1) {
        int x = (t >= d) ? s[t - d] : 0;
        __syncthreads();
        s[t] += x;
        __syncthreads();
    }
    bsum[t] = s[t];
}
__global__ void k_scan3(int* __restrict__ off, const int* __restrict__ bsum) {
    int b = blockIdx.x, t = threadIdx.x;
    if (b > 0) off[b * 256 + t + 1] += bsum[b - 1];
    if (b == 0 && t == 0) off[0] = 0;
}
__global__ void k_copy(const int* __restrict__ off, int* __restrict__ cur) {
    int i = blockIdx.x * 256 + threadIdx.x;
    if (i < N_NODES) cur[i] = off[i];
}
__global__ void k_fill(const int* __restrict__ esrc, const int* __restrict__ edst,
                       int* cur, int* __restrict__ srcs, int* __restrict__ dsts) {
    int i = blockIdx.x * 256 + threadIdx.x;
    if (i >= TOT_E) return;
    int s, d;
    if (i < N_EDGES) { s = esrc[i]; d = edst[i]; }
    else             { s = d = i - N_EDGES; }
    int p = atomicAdd(&cur[d], 1);
    srcs[p] = s;
    dsts[p] = d;
}

// ---------------- per-(edge,head) unnormalized attention weight ----------------
__global__ __launch_bounds__(256) void edge_alpha(
    const int* __restrict__ srcs, const int* __restrict__ dsts,
    const float* __restrict__ aS, const float* __restrict__ aD,
    float* __restrict__ ealpha)
{
    int i = blockIdx.x * 256 + threadIdx.x;      // over TOT_E*HEADS
    int o = i >> 3, h = i & 7;
    int s = srcs[o], d = dsts[o];
    float x = aS[s * HEADS + h] + aD[d * HEADS + h];
    x = x > 0.f ? x : 0.2f * x;
    ealpha[i] = expf(x);
}

// ---------------- GAT aggregation: single pass, precomputed weights ----------------
__global__ __launch_bounds__(256) void gat_aggregate(
    const u16* __restrict__ h, const float* __restrict__ ealpha,
    const int* __restrict__ off, const int* __restrict__ srcs,
    const float* __restrict__ bias, u16* __restrict__ out)
{
    int gid  = blockIdx.x * blockDim.x + threadIdx.x;
    int n    = gid >> 6;
    if (n >= N_NODES) return;
    int lane = threadIdx.x & 63;
    int head = lane >> 3;
    int o0 = off[n], o1 = off[n + 1];
    float denom = 0.f;
    float acc[8] = {};
    for (int o = o0; o < o1; ++o) {
        int s = srcs[o];
        float e = ealpha[o * HEADS + head];
        denom += e;
        uint4 q = *(const uint4*)(h + (size_t)s * GOUT + lane * 8);
        acc[0] += e * bf2f(q.x & 0xffff); acc[1] += e * bf2f(q.x >> 16);
        acc[2] += e * bf2f(q.y & 0xffff); acc[3] += e * bf2f(q.y >> 16);
        acc[4] += e * bf2f(q.z & 0xffff); acc[5] += e * bf2f(q.z >> 16);
        acc[6] += e * bf2f(q.w & 0xffff); acc[7] += e * bf2f(q.w >> 16);
    }
    float inv = 1.f / (denom + 1e-16f);
    int c0 = lane * 8;
    float r[8];
    #pragma unroll
    for (int j = 0; j < 8; ++j) {
        float v = acc[j] * inv + bias[c0 + j];
        r[j] = v > 0.f ? v : expm1f(v);
    }
    uint4 w;
    w.x = (u32)f2bf(r[0]) | ((u32)f2bf(r[1]) << 16);
    w.y = (u32)f2bf(r[2]) | ((u32)f2bf(r[3]) << 16);
    w.z = (u32)f2bf(r[4]) | ((u32)f2bf(r[5]) << 16);
    w.w = (u32)f2bf(r[6]) | ((u32)f2bf(r[7]) << 16);
    *(uint4*)(out + (size_t)n * GOUT + c0) = w;
}

// ---------------- global mean pool ----------------
__global__ __launch_bounds__(256) void pool_kernel(
    const u16* __restrict__ x, const int* __restrict__ batch, float* __restrict__ cbuf)
{
    int b = blockIdx.x;
    int lo = 0, hi = N_NODES;
    while (lo < hi) { int mid = (lo + hi) >> 1; if (batch[mid] < b) lo = mid + 1; else hi = mid; }
    int start = lo;
    hi = N_NODES;
    while (lo < hi) { int mid = (lo + hi) >> 1; if (batch[mid] < b + 1) lo = mid + 1; else hi = mid; }
    int end = lo;
    int t = threadIdx.x;
    float s0 = 0.f, s1 = 0.f;
    for (int i = start; i < end; ++i) {
        s0 += bf2f(x[(size_t)i * GOUT + t]);
        s1 += bf2f(x[(size_t)i * GOUT + t + 256]);
    }
    float sc = 1.f / fmaxf((float)(end - start), 1.f);
    cbuf[(size_t)b * 1024 + t]       = s0 * sc;
    cbuf[(size_t)b * 1024 + t + 256] = s1 * sc;
}

extern "C" void kernel_launch(void* const* d_in, const int* in_sizes, int n_in,
                              void* d_out, int out_size, void* d_ws, size_t ws_size,
                              hipStream_t stream)
{
    const float* x     = (const float*)d_in[0];
    const int*   ei    = (const int*)  d_in[1];
    const int*   batch = (const int*)  d_in[2];
    const float* x_gen = (const float*)d_in[3];
    const float* W1    = (const float*)d_in[4];
    const float* as1   = (const float*)d_in[5];
    const float* ad1   = (const float*)d_in[6];
    const float* b1    = (const float*)d_in[7];
    const float* W2    = (const float*)d_in[8];
    const float* as2   = (const float*)d_in[9];
    const float* ad2   = (const float*)d_in[10];
    const float* b2    = (const float*)d_in[11];
    const float* gW1   = (const float*)d_in[12];
    const float* gb1   = (const float*)d_in[13];
    const float* bng   = (const float*)d_in[14];
    const float* bnb   = (const float*)d_in[15];
    const float* bnm   = (const float*)d_in[16];
    const float* bnv   = (const float*)d_in[17];
    const float* gW2   = (const float*)d_in[18];
    const float* gb2   = (const float*)d_in[19];
    const float* fW1   = (const float*)d_in[20];
    const float* fb1   = (const float*)d_in[21];
    const float* fW2   = (const float*)d_in[22];
    const float* fb2   = (const float*)d_in[23];
    const float* fW3   = (const float*)d_in[24];
    const float* fb3   = (const float*)d_in[25];
    float* out = (float*)d_out;

    char* ws = (char*)d_ws;
    size_t off_b = 0;
    auto alloc = [&](size_t bytes) -> void* {
        void* p = ws + off_b;
        off_b += (bytes + 255) & ~(size_t)255;
        return p;
    };
    u16*   bufA    = (u16*)  alloc((size_t)N_NODES * GOUT * 2);   // bf16 features
    u16*   bufB    = (u16*)  alloc((size_t)N_NODES * GOUT * 2);   // bf16 features
    u16*   xb      = (u16*)  alloc((size_t)N_NODES * K1PAD * 2);  // x bf16, K-padded
    u16*   w1t     = (u16*)  alloc((size_t)GOUT * K1PAD * 2);     // W1^T bf16 padded
    u16*   w2t     = (u16*)  alloc((size_t)GOUT * GOUT * 2);      // W2^T bf16
    float* aSp     = (float*)alloc((size_t)N_NODES * HEADS * 4);
    float* aDp     = (float*)alloc((size_t)N_NODES * HEADS * 4);
    int*   csr_off = (int*)  alloc((size_t)(N_NODES + 1) * 4);
    int*   csr_cur = (int*)  alloc((size_t)N_NODES * 4);
    int*   bsum    = (int*)  alloc(256 * 4);
    int*   csr_src = (int*)  alloc((size_t)TOT_E * 4);
    int*   csr_dst = (int*)  alloc((size_t)TOT_E * 4);
    float* ealpha  = (float*)alloc((size_t)TOT_E * HEADS * 4);
    float* cbuf    = (float*)alloc((size_t)BATCHSZ * 1024 * 4);   // [g | unused]

    if (off_b > ws_size) return;   // clean no-op beats a memory fault

    const int* esrc = ei;
    const int* edst = ei + N_EDGES;

    // ---- conversions (bf16 weights/inputs for MFMA) ----
    conv_x_pad<<<(N_NODES * K1PAD) / 256, 256, 0, stream>>>(x, xb);
    conv_w1t<<<(GOUT * K1PAD) / 256, 256, 0, stream>>>(W1, w1t);
    conv_w2t<<<(GOUT * GOUT) / 256, 256, 0, stream>>>(W2, w2t);

    // ---- CSR by destination ----
    k_init_counts<<<N_NODES / 256, 256, 0, stream>>>(csr_cur);
    k_count<<<N_EDGES / 256, 256, 0, stream>>>(edst, csr_cur);
    k_scan1<<<256, 256, 0, stream>>>(csr_cur, csr_off, bsum);
    k_scan2<<<1, 256, 0, stream>>>(bsum);
    k_scan3<<<256, 256, 0, stream>>>(csr_off, bsum);
    k_copy<<<N_NODES / 256, 256, 0, stream>>>(csr_off, csr_cur);
    k_fill<<<TOT_E / 256, 256, 0, stream>>>(esrc, edst, csr_cur, csr_src, csr_dst);

    // ---- GAT layer 1 (MFMA) ----
    dim3 gMF(N_NODES / 128, GOUT / 128);
    gemm_mfma<<<gMF, 256, 0, stream>>>(xb, w1t, bufA, N_NODES, GOUT, K1PAD, GOUT);
    gat_att<<<N_NODES / 4, 256, 0, stream>>>(bufA, as1, ad1, aSp, aDp);
    edge_alpha<<<(TOT_E * HEADS) / 256, 256, 0, stream>>>(csr_src, csr_dst, aSp, aDp, ealpha);
    gat_aggregate<<<N_NODES / 4, 256, 0, stream>>>(bufA, ealpha, csr_off, csr_src, b1, bufB);

    // ---- GAT layer 2 (MFMA) ----
    gemm_mfma<<<gMF, 256, 0, stream>>>(bufB, w2t, bufA, N_NODES, GOUT, GOUT, GOUT);
    gat_att<<<N_NODES / 4, 256, 0, stream>>>(bufA, as2, ad2, aSp, aDp);
    edge_alpha<<<(TOT_E * HEADS) / 256, 256, 0, stream>>>(csr_src, csr_dst, aSp, aDp, ealpha);
    gat_aggregate<<<N_NODES / 4, 256, 0, stream>>>(bufA, ealpha, csr_off, csr_src, b2, bufB);

    // ---- pool (writes g into cbuf[:, 0:512)) ----
    pool_kernel<<<BATCHSZ, 256, 0, stream>>>(bufB, batch, cbuf);

    // ---- fused MLP: geno encoder + fusion head + final dot ----
    fused_mlp<<<BATCHSZ / RPB, 256, 0, stream>>>(
        x_gen, cbuf,
        gW1, gb1, bng, bnb, bnm, bnv,
        gW2, gb2, fW1, fb1, fW2, fb2, fW3, fb3,
        out);
}

// Round 13
// 549.777 us; speedup vs baseline: 1.3526x; 1.1096x over previous
//
#include <hip/hip_runtime.h>
#include <hip/hip_bf16.h>
#include <math.h>

#define N_NODES 65536
#define N_EDGES 262144
#define BATCHSZ 2048
#define F_IN    78
#define K1PAD   96
#define GENES   735
#define GOUT    512
#define HEADS   8
#define HID     64
#define TOT_E   (N_EDGES + N_NODES)   // 327680
#define RPB     4                     // batch rows per fused-MLP block
#define MLP_T   512                   // fused-MLP threads per block

typedef unsigned short u16;
typedef unsigned int   u32;
typedef __attribute__((ext_vector_type(4))) float f32x4;
typedef __attribute__((ext_vector_type(8))) short bf16x8;

__device__ __forceinline__ float bf2f(u32 h) {
    u32 u = h << 16;
    return __uint_as_float(u);
}
__device__ __forceinline__ u16 f2bf(float f) {
    u32 u = __float_as_uint(f);
    u32 r = (u + 0x7FFFu + ((u >> 16) & 1u)) >> 16;   // round-to-nearest-even
    return (u16)r;
}

// ================= MFMA bf16 GEMM + fused attention coefficients =================
// C[M,N]bf16 = A[M,K]bf16 @ BT[N,K]^T.  Also emits aS/aD: per wave, the acc tile
// covers 64 rows x 64 cols = one head (wn selects head, wm/lane rows) -> each
// (row, head) has a unique writer: no atomics.
__global__ __launch_bounds__(256) void gemm_mfma(
    const u16* __restrict__ A, const u16* __restrict__ BT, u16* __restrict__ C,
    int M, int N, int K, int ldc,
    const float* __restrict__ att_src, const float* __restrict__ att_dst,
    float* __restrict__ aS, float* __restrict__ aD)
{
    __shared__ u16 Al[128 * 40];
    __shared__ u16 Bl[128 * 40];
    int t    = threadIdx.x;
    int wid  = t >> 6, lane = t & 63;
    int wm   = wid >> 1, wn = wid & 1;
    int bm   = blockIdx.x * 128, bn = blockIdx.y * 128;

    f32x4 acc[4][4] = {};

    for (int k0 = 0; k0 < K; k0 += 32) {
        #pragma unroll
        for (int i = 0; i < 2; ++i) {
            int flat = t + i * 256;          // 0..511
            int row  = flat >> 2, slot = flat & 3;
            uint4 va = *(const uint4*)(A  + (size_t)(bm + row) * K + k0 + slot * 8);
            *(uint4*)(Al + row * 40 + slot * 8) = va;
            uint4 vb = *(const uint4*)(BT + (size_t)(bn + row) * K + k0 + slot * 8);
            *(uint4*)(Bl + row * 40 + slot * 8) = vb;
        }
        __syncthreads();
        bf16x8 af[4], bfr[4];
        int r0 = wm * 64 + (lane & 15);
        int c0 = wn * 64 + (lane & 15);
        int kk = (lane >> 4) * 8;
        #pragma unroll
        for (int m = 0; m < 4; ++m)
            af[m] = *(const bf16x8*)(Al + (r0 + m * 16) * 40 + kk);
        #pragma unroll
        for (int n = 0; n < 4; ++n)
            bfr[n] = *(const bf16x8*)(Bl + (c0 + n * 16) * 40 + kk);
        #pragma unroll
        for (int m = 0; m < 4; ++m)
            #pragma unroll
            for (int n = 0; n < 4; ++n)
                acc[m][n] = __builtin_amdgcn_mfma_f32_16x16x32_bf16(af[m], bfr[n], acc[m][n], 0, 0, 0);
        __syncthreads();
    }

    // ---- fused attention coefficients (f32 acc, pre-rounding) ----
    {
        int head = (bn >> 6) + wn;           // global col block / 64
        int ci   = lane & 15;
        float sw[4], dw[4];
        #pragma unroll
        for (int n = 0; n < 4; ++n) {
            sw[n] = att_src[head * HID + ci + n * 16];
            dw[n] = att_dst[head * HID + ci + n * 16];
        }
        #pragma unroll
        for (int m = 0; m < 4; ++m)
            #pragma unroll
            for (int j = 0; j < 4; ++j) {
                float vS = 0.f, vD = 0.f;
                #pragma unroll
                for (int n = 0; n < 4; ++n) {
                    float a = acc[m][n][j];
                    vS += a * sw[n];
                    vD += a * dw[n];
                }
                vS += __shfl_xor(vS, 1); vS += __shfl_xor(vS, 2);
                vS += __shfl_xor(vS, 4); vS += __shfl_xor(vS, 8);
                vD += __shfl_xor(vD, 1); vD += __shfl_xor(vD, 2);
                vD += __shfl_xor(vD, 4); vD += __shfl_xor(vD, 8);
                if ((lane & 15) == 0) {
                    int row = bm + wm * 64 + (lane >> 4) * 4 + m * 16 + j;
                    aS[row * HEADS + head] = vS;
                    aD[row * HEADS + head] = vD;
                }
            }
    }

    int rbase = bm + wm * 64 + (lane >> 4) * 4;
    int cbase = bn + wn * 64 + (lane & 15);
    #pragma unroll
    for (int m = 0; m < 4; ++m)
        #pragma unroll
        for (int n = 0; n < 4; ++n) {
            int col = cbase + n * 16;
            #pragma unroll
            for (int j = 0; j < 4; ++j) {
                int row = rbase + m * 16 + j;
                C[(size_t)row * ldc + col] = f2bf(acc[m][n][j]);
            }
        }
}

// ---- weight/input conversion: f32 -> bf16 (optionally transposed / K-padded) ----
__global__ void conv_x_pad(const float* __restrict__ x, u16* __restrict__ xb) {
    int i = blockIdx.x * 256 + threadIdx.x;          // over N_NODES*K1PAD
    int row = i / K1PAD, col = i - row * K1PAD;
    xb[i] = (col < F_IN) ? f2bf(x[(size_t)row * F_IN + col]) : (u16)0;
}
__global__ void conv_w1t(const float* __restrict__ W, u16* __restrict__ WT) {
    int i = blockIdx.x * 256 + threadIdx.x;          // over GOUT*K1PAD
    int n = i / K1PAD, k = i - n * K1PAD;
    WT[i] = (k < F_IN) ? f2bf(W[(size_t)k * GOUT + n]) : (u16)0;
}
__global__ void conv_w2t(const float* __restrict__ W, u16* __restrict__ WT) {
    int i = blockIdx.x * 256 + threadIdx.x;          // over GOUT*GOUT
    int n = i >> 9, k = i & 511;
    WT[i] = f2bf(W[(size_t)k * GOUT + n]);
}

// ================= fused MLP: 512 threads, deep split-K =================
// Per row: z1 = relu(bn(x_gen@gW1+gb1))[128]; z2 = relu(z1@gW2+gb2)[512];
// c = [g | z2][1024]; f1 = relu(c@fW1+fb1)[256]; f2 = relu(f1@fW2+fb2)[128];
// out = f2@fW3 + fb3.  K unroll 8 (batched loads); RPB rows amortize weights.
__global__ __launch_bounds__(MLP_T) void fused_mlp(
    const float* __restrict__ x_gen, const float* __restrict__ cbuf,
    const float* __restrict__ gW1, const float* __restrict__ gb1,
    const float* __restrict__ bng, const float* __restrict__ bnb,
    const float* __restrict__ bnm, const float* __restrict__ bnv,
    const float* __restrict__ gW2, const float* __restrict__ gb2,
    const float* __restrict__ fW1, const float* __restrict__ fb1,
    const float* __restrict__ fW2, const float* __restrict__ fb2,
    const float* __restrict__ fW3, const float* __restrict__ fb3,
    float* __restrict__ out)
{
    __shared__ float xs[RPB][736];       // 11776 B
    __shared__ float cs[RPB][1024];      // 16384 B  [g | z2]
    __shared__ float z1[RPB][128];       //  2048 B
    __shared__ float f1[RPB][256];       //  4096 B
    __shared__ float f2s[RPB][128];      //  2048 B
    __shared__ float red[4][RPB][128];   //  8192 B  (flat-viewed [2][RPB][256] in phase 3)
    int tid  = threadIdx.x;
    int row0 = blockIdx.x * RPB;
    float* redv = &red[0][0][0];

    #pragma unroll
    for (int r = 0; r < RPB; ++r) {
        for (int k = tid; k < GENES; k += MLP_T)
            xs[r][k] = x_gen[(size_t)(row0 + r) * GENES + k];
        for (int k = tid; k < 512; k += MLP_T)
            cs[r][k] = cbuf[(size_t)(row0 + r) * 1024 + k];
    }
    if (tid < RPB) xs[tid][735] = 0.f;
    __syncthreads();

    // ---- phase 1: z1 = relu(bn(x@gW1)), N=128, K=735, split-K x4, unroll 8 ----
    {
        int j = tid & 127, q = tid >> 7;           // q in 0..3
        int k0 = q * 184, kend = (q == 3) ? GENES : k0 + 184;
        float a[RPB] = {};
        int k = k0;
        for (; k + 8 <= kend; k += 8) {
            float bv[8];
            #pragma unroll
            for (int u = 0; u < 8; ++u) bv[u] = gW1[(size_t)(k + u) * 128 + j];
            #pragma unroll
            for (int r = 0; r < RPB; ++r) {
                float4 x0 = *(const float4*)&xs[r][k];
                float4 x1 = *(const float4*)&xs[r][k + 4];
                a[r] += x0.x*bv[0] + x0.y*bv[1] + x0.z*bv[2] + x0.w*bv[3]
                      + x1.x*bv[4] + x1.y*bv[5] + x1.z*bv[6] + x1.w*bv[7];
            }
        }
        for (; k < kend; ++k) {
            float b = gW1[(size_t)k * 128 + j];
            #pragma unroll
            for (int r = 0; r < RPB; ++r) a[r] += xs[r][k] * b;
        }
        #pragma unroll
        for (int r = 0; r < RPB; ++r) red[q][r][j] = a[r];
    }
    __syncthreads();
    {
        int r = tid >> 7, j = tid & 127;           // 512 tasks, 1/thread
        float v = red[0][r][j] + red[1][r][j] + red[2][r][j] + red[3][r][j];
        float s = bng[j] * rsqrtf(bnv[j] + 1e-5f);
        v = (v + gb1[j] - bnm[j]) * s + bnb[j];
        z1[r][j] = fmaxf(v, 0.f);
    }
    __syncthreads();

    // ---- phase 2: z2 = relu(z1@gW2+gb2) -> cs[:,512+], N=512, K=128, unroll 8 ----
    {
        int j = tid;
        float a[RPB] = {};
        for (int k = 0; k < 128; k += 8) {
            float bv[8];
            #pragma unroll
            for (int u = 0; u < 8; ++u) bv[u] = gW2[(size_t)(k + u) * 512 + j];
            #pragma unroll
            for (int r = 0; r < RPB; ++r) {
                float4 z0 = *(const float4*)&z1[r][k];
                float4 z4 = *(const float4*)&z1[r][k + 4];
                a[r] += z0.x*bv[0] + z0.y*bv[1] + z0.z*bv[2] + z0.w*bv[3]
                      + z4.x*bv[4] + z4.y*bv[5] + z4.z*bv[6] + z4.w*bv[7];
            }
        }
        #pragma unroll
        for (int r = 0; r < RPB; ++r)
            cs[r][512 + j] = fmaxf(a[r] + gb2[j], 0.f);
    }
    __syncthreads();

    // ---- phase 3: f1 = relu(c@fW1+fb1), N=256, K=1024, split-K x2, unroll 8 ----
    {
        int j = tid & 255, q = tid >> 8;           // q in 0..1
        int k0 = q * 512;
        float a[RPB] = {};
        for (int k = k0; k < k0 + 512; k += 8) {
            float bv[8];
            #pragma unroll
            for (int u = 0; u < 8; ++u) bv[u] = fW1[(size_t)(k + u) * 256 + j];
            #pragma unroll
            for (int r = 0; r < RPB; ++r) {
                float4 c0 = *(const float4*)&cs[r][k];
                float4 c1 = *(const float4*)&cs[r][k + 4];
                a[r] += c0.x*bv[0] + c0.y*bv[1] + c0.z*bv[2] + c0.w*bv[3]
                      + c1.x*bv[4] + c1.y*bv[5] + c1.z*bv[6] + c1.w*bv[7];
            }
        }
        #pragma unroll
        for (int r = 0; r < RPB; ++r)
            redv[(q * RPB + r) * 256 + j] = a[r];  // exactly fills the 2048-float red
    }
    __syncthreads();
    {
        #pragma unroll
        for (int i = 0; i < 2; ++i) {              // 1024 tasks, 2/thread
            int task = tid + i * MLP_T;
            int r = task >> 8, j = task & 255;
            float v = redv[r * 256 + j] + redv[(RPB + r) * 256 + j] + fb1[j];
            f1[r][j] = fmaxf(v, 0.f);
        }
    }
    __syncthreads();

    // ---- phase 4: f2 = relu(f1@fW2+fb2), N=128, K=256, split-K x4, unroll 8 ----
    {
        int j = tid & 127, q = tid >> 7;
        int k0 = q * 64;
        float a[RPB] = {};
        for (int k = k0; k < k0 + 64; k += 8) {
            float bv[8];
            #pragma unroll
            for (int u = 0; u < 8; ++u) bv[u] = fW2[(size_t)(k + u) * 128 + j];
            #pragma unroll
            for (int r = 0; r < RPB; ++r) {
                float4 c0 = *(const float4*)&f1[r][k];
                float4 c1 = *(const float4*)&f1[r][k + 4];
                a[r] += c0.x*bv[0] + c0.y*bv[1] + c0.z*bv[2] + c0.w*bv[3]
                      + c1.x*bv[4] + c1.y*bv[5] + c1.z*bv[6] + c1.w*bv[7];
            }
        }
        #pragma unroll
        for (int r = 0; r < RPB; ++r) red[q][r][j] = a[r];
    }
    __syncthreads();
    {
        int r = tid >> 7, j = tid & 127;           // 512 tasks, 1/thread
        float v = red[0][r][j] + red[1][r][j] + red[2][r][j] + red[3][r][j] + fb2[j];
        f2s[r][j] = fmaxf(v, 0.f);
    }
    __syncthreads();

    // ---- phase 5: out = f2@fW3 + fb3; wave w handles row w (waves 4..7 idle) ----
    {
        int r = tid >> 6, l = tid & 63;
        if (r < RPB) {
            float v = f2s[r][l] * fW3[l] + f2s[r][l + 64] * fW3[l + 64];
            v += __shfl_xor(v, 32); v += __shfl_xor(v, 16); v += __shfl_xor(v, 8);
            v += __shfl_xor(v, 4);  v += __shfl_xor(v, 2);  v += __shfl_xor(v, 1);
            if (l == 0) out[row0 + r] = v + fb3[0];
        }
    }
}

// ---------------- CSR build ----------------
__global__ void k_init_counts(int* cnt) {
    int i = blockIdx.x * 256 + threadIdx.x;
    if (i < N_NODES) cnt[i] = 1;             // self-loop
}
__global__ void k_count(const int* __restrict__ dst, int* cnt) {
    int e = blockIdx.x * 256 + threadIdx.x;
    if (e < N_EDGES) atomicAdd(&cnt[dst[e]], 1);
}
__global__ void k_scan1(const int* __restrict__ cnt, int* __restrict__ off, int* __restrict__ bsum) {
    __shared__ int s[256];
    int b = blockIdx.x, t = threadIdx.x;
    s[t] = cnt[b * 256 + t]; __syncthreads();
    for (int d = 1; d < 256; d <<= 1) {
        int x = (t >= d) ? s[t - d] : 0;
        __syncthreads();
        s[t] += x;
        __syncthreads();
    }
    off[b * 256 + t + 1] = s[t];
    if (t == 255) bsum[b] = s[255];
}
__global__ void k_scan2(int* bsum) {
    __shared__ int s[256];
    int t = threadIdx.x;
    s[t] = bsum[t]; __syncthreads();
    for (int d = 1; d < 256; d <<= 1) {
        int x = (t >= d) ? s[t - d] : 0;
        __syncthreads();
        s[t] += x;
        __syncthreads();
    }
    bsum[t] = s[t];
}
__global__ void k_scan3(int* __restrict__ off, const int* __restrict__ bsum) {
    int b = blockIdx.x, t = threadIdx.x;
    if (b > 0) off[b * 256 + t + 1] += bsum[b - 1];
    if (b == 0 && t == 0) off[0] = 0;
}
__global__ void k_copy(const int* __restrict__ off, int* __restrict__ cur) {
    int i = blockIdx.x * 256 + threadIdx.x;
    if (i < N_NODES) cur[i] = off[i];
}
__global__ void k_fill(const int* __restrict__ esrc, const int* __restrict__ edst,
                       int* cur, int* __restrict__ srcs, int* __restrict__ dsts) {
    int i = blockIdx.x * 256 + threadIdx.x;
    if (i >= TOT_E) return;
    int s, d;
    if (i < N_EDGES) { s = esrc[i]; d = edst[i]; }
    else             { s = d = i - N_EDGES; }
    int p = atomicAdd(&cur[d], 1);
    srcs[p] = s;
    dsts[p] = d;
}

// ---------------- per-(edge,head) unnormalized attention weight ----------------
__global__ __launch_bounds__(256) void edge_alpha(
    const int* __restrict__ srcs, const int* __restrict__ dsts,
    const float* __restrict__ aS, const float* __restrict__ aD,
    float* __restrict__ ealpha)
{
    int i = blockIdx.x * 256 + threadIdx.x;      // over TOT_E*HEADS
    int o = i >> 3, h = i & 7;
    int s = srcs[o], d = dsts[o];
    float x = aS[s * HEADS + h] + aD[d * HEADS + h];
    x = x > 0.f ? x : 0.2f * x;
    ealpha[i] = expf(x);
}

// ---------------- GAT aggregation: single pass, precomputed weights ----------------
__global__ __launch_bounds__(256) void gat_aggregate(
    const u16* __restrict__ h, const float* __restrict__ ealpha,
    const int* __restrict__ off, const int* __restrict__ srcs,
    const float* __restrict__ bias, u16* __restrict__ out)
{
    int gid  = blockIdx.x * blockDim.x + threadIdx.x;
    int n    = gid >> 6;
    if (n >= N_NODES) return;
    int lane = threadIdx.x & 63;
    int head = lane >> 3;
    int o0 = off[n], o1 = off[n + 1];
    float denom = 0.f;
    float acc[8] = {};
    for (int o = o0; o < o1; ++o) {
        int s = srcs[o];
        float e = ealpha[o * HEADS + head];
        denom += e;
        uint4 q = *(const uint4*)(h + (size_t)s * GOUT + lane * 8);
        acc[0] += e * bf2f(q.x & 0xffff); acc[1] += e * bf2f(q.x >> 16);
        acc[2] += e * bf2f(q.y & 0xffff); acc[3] += e * bf2f(q.y >> 16);
        acc[4] += e * bf2f(q.z & 0xffff); acc[5] += e * bf2f(q.z >> 16);
        acc[6] += e * bf2f(q.w & 0xffff); acc[7] += e * bf2f(q.w >> 16);
    }
    float inv = 1.f / (denom + 1e-16f);
    int c0 = lane * 8;
    float r[8];
    #pragma unroll
    for (int j = 0; j < 8; ++j) {
        float v = acc[j] * inv + bias[c0 + j];
        r[j] = v > 0.f ? v : expm1f(v);
    }
    uint4 w;
    w.x = (u32)f2bf(r[0]) | ((u32)f2bf(r[1]) << 16);
    w.y = (u32)f2bf(r[2]) | ((u32)f2bf(r[3]) << 16);
    w.z = (u32)f2bf(r[4]) | ((u32)f2bf(r[5]) << 16);
    w.w = (u32)f2bf(r[6]) | ((u32)f2bf(r[7]) << 16);
    *(uint4*)(out + (size_t)n * GOUT + c0) = w;
}

// ---------------- global mean pool ----------------
__global__ __launch_bounds__(256) void pool_kernel(
    const u16* __restrict__ x, const int* __restrict__ batch, float* __restrict__ cbuf)
{
    int b = blockIdx.x;
    int lo = 0, hi = N_NODES;
    while (lo < hi) { int mid = (lo + hi) >> 1; if (batch[mid] < b) lo = mid + 1; else hi = mid; }
    int start = lo;
    hi = N_NODES;
    while (lo < hi) { int mid = (lo + hi) >> 1; if (batch[mid] < b + 1) lo = mid + 1; else hi = mid; }
    int end = lo;
    int t = threadIdx.x;
    float s0 = 0.f, s1 = 0.f;
    for (int i = start; i < end; ++i) {
        s0 += bf2f(x[(size_t)i * GOUT + t]);
        s1 += bf2f(x[(size_t)i * GOUT + t + 256]);
    }
    float sc = 1.f / fmaxf((float)(end - start), 1.f);
    cbuf[(size_t)b * 1024 + t]       = s0 * sc;
    cbuf[(size_t)b * 1024 + t + 256] = s1 * sc;
}

extern "C" void kernel_launch(void* const* d_in, const int* in_sizes, int n_in,
                              void* d_out, int out_size, void* d_ws, size_t ws_size,
                              hipStream_t stream)
{
    const float* x     = (const float*)d_in[0];
    const int*   ei    = (const int*)  d_in[1];
    const int*   batch = (const int*)  d_in[2];
    const float* x_gen = (const float*)d_in[3];
    const float* W1    = (const float*)d_in[4];
    const float* as1   = (const float*)d_in[5];
    const float* ad1   = (const float*)d_in[6];
    const float* b1    = (const float*)d_in[7];
    const float* W2    = (const float*)d_in[8];
    const float* as2   = (const float*)d_in[9];
    const float* ad2   = (const float*)d_in[10];
    const float* b2    = (const float*)d_in[11];
    const float* gW1   = (const float*)d_in[12];
    const float* gb1   = (const float*)d_in[13];
    const float* bng   = (const float*)d_in[14];
    const float* bnb   = (const float*)d_in[15];
    const float* bnm   = (const float*)d_in[16];
    const float* bnv   = (const float*)d_in[17];
    const float* gW2   = (const float*)d_in[18];
    const float* gb2   = (const float*)d_in[19];
    const float* fW1   = (const float*)d_in[20];
    const float* fb1   = (const float*)d_in[21];
    const float* fW2   = (const float*)d_in[22];
    const float* fb2   = (const float*)d_in[23];
    const float* fW3   = (const float*)d_in[24];
    const float* fb3   = (const float*)d_in[25];
    float* out = (float*)d_out;

    char* ws = (char*)d_ws;
    size_t off_b = 0;
    auto alloc = [&](size_t bytes) -> void* {
        void* p = ws + off_b;
        off_b += (bytes + 255) & ~(size_t)255;
        return p;
    };
    u16*   bufA    = (u16*)  alloc((size_t)N_NODES * GOUT * 2);   // bf16 features
    u16*   bufB    = (u16*)  alloc((size_t)N_NODES * GOUT * 2);   // bf16 features
    u16*   xb      = (u16*)  alloc((size_t)N_NODES * K1PAD * 2);  // x bf16, K-padded
    u16*   w1t     = (u16*)  alloc((size_t)GOUT * K1PAD * 2);     // W1^T bf16 padded
    u16*   w2t     = (u16*)  alloc((size_t)GOUT * GOUT * 2);      // W2^T bf16
    float* aSp     = (float*)alloc((size_t)N_NODES * HEADS * 4);
    float* aDp     = (float*)alloc((size_t)N_NODES * HEADS * 4);
    int*   csr_off = (int*)  alloc((size_t)(N_NODES + 1) * 4);
    int*   csr_cur = (int*)  alloc((size_t)N_NODES * 4);
    int*   bsum    = (int*)  alloc(256 * 4);
    int*   csr_src = (int*)  alloc((size_t)TOT_E * 4);
    int*   csr_dst = (int*)  alloc((size_t)TOT_E * 4);
    float* ealpha  = (float*)alloc((size_t)TOT_E * HEADS * 4);
    float* cbuf    = (float*)alloc((size_t)BATCHSZ * 1024 * 4);   // [g | unused]

    if (off_b > ws_size) return;   // clean no-op beats a memory fault

    const int* esrc = ei;
    const int* edst = ei + N_EDGES;

    // ---- conversions (bf16 weights/inputs for MFMA) ----
    conv_x_pad<<<(N_NODES * K1PAD) / 256, 256, 0, stream>>>(x, xb);
    conv_w1t<<<(GOUT * K1PAD) / 256, 256, 0, stream>>>(W1, w1t);
    conv_w2t<<<(GOUT * GOUT) / 256, 256, 0, stream>>>(W2, w2t);

    // ---- CSR by destination ----
    k_init_counts<<<N_NODES / 256, 256, 0, stream>>>(csr_cur);
    k_count<<<N_EDGES / 256, 256, 0, stream>>>(edst, csr_cur);
    k_scan1<<<256, 256, 0, stream>>>(csr_cur, csr_off, bsum);
    k_scan2<<<1, 256, 0, stream>>>(bsum);
    k_scan3<<<256, 256, 0, stream>>>(csr_off, bsum);
    k_copy<<<N_NODES / 256, 256, 0, stream>>>(csr_off, csr_cur);
    k_fill<<<TOT_E / 256, 256, 0, stream>>>(esrc, edst, csr_cur, csr_src, csr_dst);

    // ---- GAT layer 1 (MFMA + fused att) ----
    dim3 gMF(N_NODES / 128, GOUT / 128);
    gemm_mfma<<<gMF, 256, 0, stream>>>(xb, w1t, bufA, N_NODES, GOUT, K1PAD, GOUT,
                                       as1, ad1, aSp, aDp);
    edge_alpha<<<(TOT_E * HEADS) / 256, 256, 0, stream>>>(csr_src, csr_dst, aSp, aDp, ealpha);
    gat_aggregate<<<N_NODES / 4, 256, 0, stream>>>(bufA, ealpha, csr_off, csr_src, b1, bufB);

    // ---- GAT layer 2 (MFMA + fused att) ----
    gemm_mfma<<<gMF, 256, 0, stream>>>(bufB, w2t, bufA, N_NODES, GOUT, GOUT, GOUT,
                                       as2, ad2, aSp, aDp);
    edge_alpha<<<(TOT_E * HEADS) / 256, 256, 0, stream>>>(csr_src, csr_dst, aSp, aDp, ealpha);
    gat_aggregate<<<N_NODES / 4, 256, 0, stream>>>(bufA, ealpha, csr_off, csr_src, b2, bufB);

    // ---- pool (writes g into cbuf[:, 0:512)) ----
    pool_kernel<<<BATCHSZ, 256, 0, stream>>>(bufB, batch, cbuf);

    // ---- fused MLP: geno encoder + fusion head + final dot ----
    fused_mlp<<<BATCHSZ / RPB, MLP_T, 0, stream>>>(
        x_gen, cbuf,
        gW1, gb1, bng, bnb, bnm, bnv,
        gW2, gb2, fW1, fb1, fW2, fb2, fW3, fb3,
        out);
}